// Round 1
// baseline (1579.416 us; speedup 1.0000x reference)
//
#include <hip/hip_runtime.h>
#include <math.h>

// ---------------- problem constants ----------------
#define B_INS 8192
#define D 128
#define N_INS 16384       // 2*B_INS
#define BP 256
#define P 256
#define NP 512            // 2*P
#define INV_T 10.0f       // 1/TEMP
#define SHIFT 10.0f       // |logit| <= 10 since embeddings are unit-norm

// tile config
#define TM 64
#define TN 64
#define LS 66             // LDS leading-dim pad: bank = (2k + c) % 32 -> 2-way max (free)
#define CSPLIT 4
#define COLS_PER (N_INS / CSPLIT)   // 4096

// ---------------- workspace layout (floats) ----------------
// [0..8)                acc: acc[0] = ins sum, acc[1] = patch sum
// [8 .. 8+16384)        S_ins   (zeroed each launch)
// [.. +16384)           pos_ins (zeroed each launch)
// [.. +16384)           invI
// [.. +131072)          invP  (BP * NP)
#define WS_ACC  0
#define WS_S    8
#define WS_POS  (8 + 16384)
#define WS_INVI (8 + 2 * 16384)
#define WS_INVP (WS_INVI + 16384)
#define WS_ZERO_FLOATS (8 + 2 * 16384)

// ---------------- norm kernels ----------------
__global__ void norm_ins_k(const float* __restrict__ v1, const float* __restrict__ v2,
                           float* __restrict__ invI) {
    int i = blockIdx.x * blockDim.x + threadIdx.x;
    if (i >= N_INS) return;
    const float* p = (i < B_INS) ? (v1 + (size_t)i * D) : (v2 + (size_t)(i - B_INS) * D);
    float ss = 0.f;
#pragma unroll
    for (int k = 0; k < D; k += 4) {
        float4 v = *(const float4*)(p + k);
        ss += v.x * v.x + v.y * v.y + v.z * v.z + v.w * v.w;
    }
    invI[i] = 1.0f / fmaxf(sqrtf(ss), 1e-12f);
}

__global__ void norm_patch_k(const float* __restrict__ v1, const float* __restrict__ v2,
                             float* __restrict__ invP) {
    int idx = blockIdx.x * blockDim.x + threadIdx.x;   // over BP*NP
    if (idx >= BP * NP) return;
    int b = idx / NP, i = idx - b * NP;
    const float* src = (i < P) ? v1 : v2;
    int p = (i < P) ? i : i - P;
    const float* base = src + (size_t)b * D * P + p;
    float ss = 0.f;
#pragma unroll 8
    for (int d = 0; d < D; d++) { float v = base[(size_t)d * P]; ss += v * v; }
    invP[idx] = 1.0f / fmaxf(sqrtf(ss), 1e-12f);
}

// ---------------- shared inner FMA block ----------------
// acc[4][4] += A-col-slice(ty) outer B-col-slice(tx), K=64 from LDS.
__device__ __forceinline__ void fma_block(const float (*As)[LS], int kc,
                                          const float (*Bs)[LS],
                                          int ty, int tx, float acc[4][4]) {
#pragma unroll 8
    for (int k = 0; k < 64; k++) {
        const float* ar = &As[kc + k][0];
        const float* br = &Bs[k][0];
        float2 a01 = *(const float2*)(ar + (ty << 2));
        float2 a23 = *(const float2*)(ar + (ty << 2) + 2);
        float2 b01 = *(const float2*)(br + (tx << 2));
        float2 b23 = *(const float2*)(br + (tx << 2) + 2);
        float a[4] = {a01.x, a01.y, a23.x, a23.y};
        float b[4] = {b01.x, b01.y, b23.x, b23.y};
#pragma unroll
        for (int m = 0; m < 4; m++)
#pragma unroll
            for (int n = 0; n < 4; n++) acc[m][n] += a[m] * b[n];
    }
}

// ---------------- instance CE ----------------
// grid = (N_INS/TM, CSPLIT); block = 256.
// Each block: rows [bx*64, +64), columns [by*4096, +4096) in 64-wide tiles.
// Accumulates partial S (sum of exp(logit-10), diag skipped) and positive logit
// into global arrays via atomics; finalize kernel does log + mean.
__global__ __launch_bounds__(256) void ins_ce_k(const float* __restrict__ v1,
                                                const float* __restrict__ v2,
                                                const float* __restrict__ invI,
                                                float* __restrict__ S_ins,
                                                float* __restrict__ pos_ins) {
    __shared__ float As[D][LS];    // 33792 B
    __shared__ float Bs[64][LS];   // 16896 B
    int t = threadIdx.x;
    int tx = t & 15, ty = t >> 4;
    int rowBase = blockIdx.x * TM;
    int colStart = blockIdx.y * COLS_PER;

    // Load A tile, full K. 2048 float4s, 8 per thread. Global reads coalesced
    // (32 consecutive float4 per row-half-wave). LDS layout k-major.
#pragma unroll
    for (int it = 0; it < 8; it++) {
        int fi = it * 256 + t;
        int r = fi >> 5;
        int k4 = fi & 31;
        int i = rowBase + r;
        const float* p = (i < B_INS) ? (v1 + (size_t)i * D) : (v2 + (size_t)(i - B_INS) * D);
        float4 v = *(const float4*)(p + (k4 << 2));
        As[(k4 << 2) + 0][r] = v.x;
        As[(k4 << 2) + 1][r] = v.y;
        As[(k4 << 2) + 2][r] = v.z;
        As[(k4 << 2) + 3][r] = v.w;
    }

    float invR[4];
    int rowIdx[4], label[4];
#pragma unroll
    for (int m = 0; m < 4; m++) {
        rowIdx[m] = rowBase + (ty << 2) + m;
        invR[m] = invI[rowIdx[m]];
        label[m] = (rowIdx[m] < B_INS) ? rowIdx[m] + B_INS : rowIdx[m] - B_INS;
    }

    float S[4] = {0.f, 0.f, 0.f, 0.f};
    float posv[4] = {0.f, 0.f, 0.f, 0.f};

    for (int ct = 0; ct < COLS_PER / TN; ct++) {
        int colBase = colStart + ct * TN;
        float acc[4][4] = {};
#pragma unroll
        for (int kc = 0; kc < D; kc += 64) {
            __syncthreads();   // protect Bs from previous iteration's readers
#pragma unroll
            for (int it = 0; it < 4; it++) {
                int fi = it * 256 + t;
                int c = fi >> 4;
                int k4 = fi & 15;
                int j = colBase + c;
                const float* p = (j < B_INS) ? (v1 + (size_t)j * D) : (v2 + (size_t)(j - B_INS) * D);
                float4 v = *(const float4*)(p + kc + (k4 << 2));
                Bs[(k4 << 2) + 0][c] = v.x;
                Bs[(k4 << 2) + 1][c] = v.y;
                Bs[(k4 << 2) + 2][c] = v.z;
                Bs[(k4 << 2) + 3][c] = v.w;
            }
            __syncthreads();
            fma_block(As, kc, Bs, ty, tx, acc);
        }
        // epilogue for this 64x64 tile
        float4 invC4 = *(const float4*)&invI[colBase + (tx << 2)];
        float invC[4] = {invC4.x, invC4.y, invC4.z, invC4.w};
#pragma unroll
        for (int n = 0; n < 4; n++) {
            int j = colBase + (tx << 2) + n;
#pragma unroll
            for (int m = 0; m < 4; m++) {
                float l = acc[m][n] * invR[m] * invC[n] * INV_T;
                if (j != rowIdx[m]) S[m] += __expf(l - SHIFT);
                if (j == label[m]) posv[m] = l;
            }
        }
    }

    // reduce across the 16 tx lanes (16-lane subgroups within the wave)
#pragma unroll
    for (int off = 8; off >= 1; off >>= 1) {
#pragma unroll
        for (int m = 0; m < 4; m++) {
            S[m] += __shfl_down(S[m], off, 16);
            posv[m] += __shfl_down(posv[m], off, 16);
        }
    }
    if (tx == 0) {
#pragma unroll
        for (int m = 0; m < 4; m++) {
            atomicAdd(&S_ins[rowIdx[m]], S[m]);
            atomicAdd(&pos_ins[rowIdx[m]], posv[m]);   // only owning column-split adds nonzero
        }
    }
}

// ---------------- patch CE ----------------
// grid = (NP/TM, BP); block = 256. Each block: one batch b, 64 rows, all 512 cols.
__global__ __launch_bounds__(256) void patch_ce_k(const float* __restrict__ v1p,
                                                  const float* __restrict__ v2p,
                                                  const int* __restrict__ c1,
                                                  const int* __restrict__ c2,
                                                  const float* __restrict__ invP,
                                                  float* __restrict__ acc_out) {
    __shared__ float As[D][LS];
    __shared__ float Bs[64][LS];
    __shared__ float partial[16];
    int t = threadIdx.x;
    int tx = t & 15, ty = t >> 4;
    int b = blockIdx.y;
    int rowBase = blockIdx.x * TM;   // within [0, 512)
    const float* base1 = v1p + (size_t)b * D * P;
    const float* base2 = v2p + (size_t)b * D * P;

    // Load A tile: 64 rows (embedding index i), 128 k. Element (k, i) = src[k*P + p].
    // 64-wide tiles never straddle the P=256 source boundary.
    {
        const float* src = (rowBase < P) ? base1 : base2;
        int p0 = (rowBase < P) ? rowBase : rowBase - P;
#pragma unroll
        for (int it = 0; it < 32; it++) {
            int l = it * 256 + t;
            int r = l & 63, k = l >> 6;
            As[k][r] = src[(size_t)k * P + p0 + r];
        }
    }

    float invR[4];
    int rowIdx[4], label[4];
#pragma unroll
    for (int m = 0; m < 4; m++) {
        rowIdx[m] = rowBase + (ty << 2) + m;
        invR[m] = invP[b * NP + rowIdx[m]];
        label[m] = (rowIdx[m] < P) ? rowIdx[m] + P : rowIdx[m] - P;
    }

    float S[4] = {0.f, 0.f, 0.f, 0.f};
    float posv[4] = {0.f, 0.f, 0.f, 0.f};

    for (int ct = 0; ct < NP / TN; ct++) {   // 8 column tiles
        int colBase = ct * TN;
        const float* src = (colBase < P) ? base1 : base2;
        int q0 = (colBase < P) ? colBase : colBase - P;
        float acc[4][4] = {};
#pragma unroll
        for (int kc = 0; kc < D; kc += 64) {
            __syncthreads();
#pragma unroll
            for (int it = 0; it < 16; it++) {
                int l = it * 256 + t;
                int c = l & 63, k = l >> 6;
                Bs[k][c] = src[(size_t)(kc + k) * P + q0 + c];
            }
            __syncthreads();
            fma_block(As, kc, Bs, ty, tx, acc);
        }
        float4 invC4 = *(const float4*)&invP[b * NP + colBase + (tx << 2)];
        float invC[4] = {invC4.x, invC4.y, invC4.z, invC4.w};
#pragma unroll
        for (int n = 0; n < 4; n++) {
            int j = colBase + (tx << 2) + n;
#pragma unroll
            for (int m = 0; m < 4; m++) {
                float l = acc[m][n] * invR[m] * invC[n] * INV_T;
                if (j != rowIdx[m]) S[m] += __expf(l - SHIFT);
                if (j == label[m]) posv[m] = l;
            }
        }
    }

#pragma unroll
    for (int off = 8; off >= 1; off >>= 1) {
#pragma unroll
        for (int m = 0; m < 4; m++) {
            S[m] += __shfl_down(S[m], off, 16);
            posv[m] += __shfl_down(posv[m], off, 16);
        }
    }
    if (tx == 0) {
        float local = 0.f;
#pragma unroll
        for (int m = 0; m < 4; m++) {
            int i = rowIdx[m];
            int cnt = (i < P) ? c1[b * P + i] : c2[b * P + i - P];
            if (cnt != 0) local += logf(S[m]) + SHIFT - posv[m];
        }
        partial[ty] = local;
    }
    __syncthreads();
    if (t == 0) {
        float s = 0.f;
#pragma unroll
        for (int q = 0; q < 16; q++) s += partial[q];
        atomicAdd(&acc_out[1], s);
    }
}

// ---------------- finalize ----------------
__global__ void fin_ins_k(const float* __restrict__ S_ins, const float* __restrict__ pos_ins,
                          float* __restrict__ acc) {
    int i = blockIdx.x * 256 + threadIdx.x;
    float v = 0.f;
    if (i < N_INS) v = logf(S_ins[i]) + SHIFT - pos_ins[i];
    int lane = threadIdx.x & 63, wave = threadIdx.x >> 6;
#pragma unroll
    for (int off = 32; off >= 1; off >>= 1) v += __shfl_down(v, off, 64);
    __shared__ float ps[4];
    if (lane == 0) ps[wave] = v;
    __syncthreads();
    if (threadIdx.x == 0) atomicAdd(&acc[0], ps[0] + ps[1] + ps[2] + ps[3]);
}

__global__ void final_k(const int* __restrict__ c1, const int* __restrict__ c2,
                        const float* __restrict__ acc, float* __restrict__ out) {
    int t = threadIdx.x;
    int cnt = 0;
    for (int i = t; i < BP * P; i += 256) {
        cnt += (c1[i] != 0) ? 1 : 0;
        cnt += (c2[i] != 0) ? 1 : 0;
    }
    float v = (float)cnt;
    int lane = t & 63, wave = t >> 6;
#pragma unroll
    for (int off = 32; off >= 1; off >>= 1) v += __shfl_down(v, off, 64);
    __shared__ float ps[4];
    if (lane == 0) ps[wave] = v;
    __syncthreads();
    if (t == 0) {
        float n_valid = ps[0] + ps[1] + ps[2] + ps[3];
        out[0] = acc[0] * (1.0f / (float)N_INS) + acc[1] / n_valid;
    }
}

// ---------------- launch ----------------
extern "C" void kernel_launch(void* const* d_in, const int* in_sizes, int n_in,
                              void* d_out, int out_size, void* d_ws, size_t ws_size,
                              hipStream_t stream) {
    const float* v1i = (const float*)d_in[0];
    const float* v2i = (const float*)d_in[1];
    const float* v1p = (const float*)d_in[2];
    const float* v2p = (const float*)d_in[3];
    const int* c1 = (const int*)d_in[4];
    const int* c2 = (const int*)d_in[5];
    float* ws = (float*)d_ws;
    float* out = (float*)d_out;

    hipMemsetAsync(ws, 0, WS_ZERO_FLOATS * sizeof(float), stream);

    norm_ins_k<<<N_INS / 256, 256, 0, stream>>>(v1i, v2i, ws + WS_INVI);
    norm_patch_k<<<(BP * NP) / 256, 256, 0, stream>>>(v1p, v2p, ws + WS_INVP);

    ins_ce_k<<<dim3(N_INS / TM, CSPLIT), 256, 0, stream>>>(v1i, v2i, ws + WS_INVI,
                                                           ws + WS_S, ws + WS_POS);
    patch_ce_k<<<dim3(NP / TM, BP), 256, 0, stream>>>(v1p, v2p, c1, c2,
                                                      ws + WS_INVP, ws + WS_ACC);

    fin_ins_k<<<N_INS / 256, 256, 0, stream>>>(ws + WS_S, ws + WS_POS, ws + WS_ACC);
    final_k<<<1, 256, 0, stream>>>(c1, c2, ws + WS_ACC, out);
}

// Round 2
// 452.996 us; speedup vs baseline: 3.4866x; 3.4866x over previous
//
#include <hip/hip_runtime.h>
#include <math.h>

typedef __bf16 bf16_t;
typedef __bf16 bf16x8 __attribute__((ext_vector_type(8)));
typedef float f32x4 __attribute__((ext_vector_type(4)));

#define B_INS 8192
#define N_INS 16384
#define D 128
#define BP 256
#define P 256
#define NP 512

// ---------------- workspace layout ----------------
// floats: [0..8) acc (acc[0]=ins sum, acc[1]=patch sum), [8..8+16384) S_ins,
//         [..+16384) pos_ins   -- all zeroed each launch.
// bytes:  EMB_I_BYTE: normalized instance embeddings, bf16 [16384][128]
//         EMB_P_BYTE: normalized patch embeddings,    bf16 [256][512][128]
#define WS_ACC 0
#define WS_S 8
#define WS_POS (8 + 16384)
#define WS_ZERO_FLOATS (8 + 2 * 16384)
#define EMB_I_BYTE (WS_ZERO_FLOATS * 4)            // 131104, 16B aligned
#define EMB_P_BYTE (EMB_I_BYTE + N_INS * D * 2)    // +4 MB, 16B aligned

// ---------------- helpers ----------------
__device__ __forceinline__ void load_lds16(const bf16_t* g, bf16_t* l) {
    __builtin_amdgcn_global_load_lds(
        (const __attribute__((address_space(1))) void*)g,
        (__attribute__((address_space(3))) void*)l, 16, 0, 0);
}

// Stage 128 rows x 128 k of bf16 (row-major, 256B rows) into LDS.
// src already offset to row 0. Wave w stages rows [w*32, w*32+32).
// Each global_load_lds: lanes 0..63 -> 1KB contiguous (4 rows).
__device__ __forceinline__ void stage_tile(const bf16_t* __restrict__ src,
                                           bf16_t* dst, int w, int lane) {
    const bf16_t* g = src + (size_t)(w * 32 + (lane >> 4)) * 128 + (lane & 15) * 8;
#pragma unroll
    for (int it = 0; it < 8; it++) {
        load_lds16(g + (size_t)it * 4 * 128, dst + (w * 32 + it * 4) * 128);
    }
}

// 128x128 output tile, K=128 resident in LDS. Wave covers 64x64 subtile
// (rh = row half, ch = col half). 16x16x32 bf16 MFMA.
// A-frag: m = lane&15, k = q*8+j ; B-frag: n = lane&15, k = q*8+j.
// C-frag: col = lane&15, row = q*4+reg.
__device__ __forceinline__ void mfma_tile(const bf16_t* shA, const bf16_t* shB,
                                          int rh, int ch, int tx, int q,
                                          f32x4 acc[4][4]) {
#pragma unroll
    for (int ks = 0; ks < 4; ks++) {
        bf16x8 af[4], bf[4];
#pragma unroll
        for (int rt = 0; rt < 4; rt++)
            af[rt] = *(const bf16x8*)(shA + (rh * 64 + rt * 16 + tx) * 128 + ks * 32 + q * 8);
#pragma unroll
        for (int nt = 0; nt < 4; nt++)
            bf[nt] = *(const bf16x8*)(shB + (ch * 64 + nt * 16 + tx) * 128 + ks * 32 + q * 8);
#pragma unroll
        for (int rt = 0; rt < 4; rt++)
#pragma unroll
            for (int nt = 0; nt < 4; nt++)
                acc[rt][nt] = __builtin_amdgcn_mfma_f32_16x16x32_bf16(
                    af[rt], bf[nt], acc[rt][nt], 0, 0, 0);
    }
}

// ---------------- normalize kernels ----------------
// One wave per instance row: fp32 norm, write bf16 normalized row.
__global__ __launch_bounds__(256) void norm_ins_k(const float* __restrict__ v1,
                                                  const float* __restrict__ v2,
                                                  bf16_t* __restrict__ embI) {
    int w = threadIdx.x >> 6, lane = threadIdx.x & 63;
    int i = blockIdx.x * 4 + w;
    const float* src = (i < B_INS) ? (v1 + (size_t)i * D) : (v2 + (size_t)(i - B_INS) * D);
    float2 v = *(const float2*)(src + lane * 2);
    float ss = v.x * v.x + v.y * v.y;
#pragma unroll
    for (int off = 32; off >= 1; off >>= 1) ss += __shfl_xor(ss, off, 64);
    float inv = 1.0f / fmaxf(sqrtf(ss), 1e-12f);
    union { bf16_t b[2]; unsigned u; } pk;
    pk.b[0] = (bf16_t)(v.x * inv);
    pk.b[1] = (bf16_t)(v.y * inv);
    *(unsigned*)(embI + (size_t)i * D + lane * 2) = pk.u;
}

// Patch: input (b, d, i) d-major; output embP[b][i][d] bf16 (transposed, normalized).
// Block handles (batch b, source half h, 64-wide i chunk) via LDS transpose.
__global__ __launch_bounds__(256) void norm_patch_k(const float* __restrict__ v1,
                                                    const float* __restrict__ v2,
                                                    bf16_t* __restrict__ embP) {
    __shared__ float L[128][65];
    __shared__ float ps[4][64];
    __shared__ float invs[64];
    int t = threadIdx.x;
    int bx = blockIdx.x;
    int b = bx >> 3, h = (bx >> 2) & 1, chunk = bx & 3;
    int i0 = chunk * 64;
    const float* src = ((h == 0) ? v1 : v2) + (size_t)b * D * P;

#pragma unroll
    for (int it = 0; it < 8; it++) {
        int fi = it * 256 + t;
        int d = fi >> 4, c4 = fi & 15;
        float4 v = *(const float4*)(src + (size_t)d * P + i0 + c4 * 4);
        L[d][c4 * 4 + 0] = v.x;
        L[d][c4 * 4 + 1] = v.y;
        L[d][c4 * 4 + 2] = v.z;
        L[d][c4 * 4 + 3] = v.w;
    }
    __syncthreads();
    {
        int col = t & 63, part = t >> 6;
        float ss = 0.f;
#pragma unroll 8
        for (int d = part * 32; d < part * 32 + 32; d++) { float x = L[d][col]; ss += x * x; }
        ps[part][col] = ss;
    }
    __syncthreads();
    if (t < 64) {
        float n2 = ps[0][t] + ps[1][t] + ps[2][t] + ps[3][t];
        invs[t] = 1.0f / fmaxf(sqrtf(n2), 1e-12f);
    }
    __syncthreads();
    // write out: rows (h*256 + i0 + ic) of length 128, bf16, pair-packed
#pragma unroll
    for (int it = 0; it < 16; it++) {
        int idx = it * 256 + t;
        int pc = idx & 63, ic = idx >> 6;
        int d = pc * 2;
        float inv = invs[ic];
        union { bf16_t b[2]; unsigned u; } pk;
        pk.b[0] = (bf16_t)(L[d][ic] * inv);
        pk.b[1] = (bf16_t)(L[d + 1][ic] * inv);
        *(unsigned*)(embP + (size_t)b * NP * D + (size_t)(h * P + i0 + ic) * D + d) = pk.u;
    }
}

// ---------------- instance CE (MFMA) ----------------
// grid (128 row-blocks, 4 col-splits). Block: 128 rows x 4096 cols in 128-wide tiles.
__global__ __launch_bounds__(256) void ins_ce_mfma(const bf16_t* __restrict__ emb,
                                                   float* __restrict__ S,
                                                   float* __restrict__ pos) {
    __shared__ __align__(16) bf16_t shA[128 * 128];
    __shared__ __align__(16) bf16_t shB[128 * 128];
    int t = threadIdx.x;
    int w = t >> 6, lane = t & 63;
    int tx = lane & 15, q = lane >> 4;
    int rh = w & 1, ch = w >> 1;
    int rowBase = blockIdx.x * 128;

    stage_tile(emb + (size_t)rowBase * 128, shA, w, lane);

    float rowS[16], posv[16];
#pragma unroll
    for (int i2 = 0; i2 < 16; i2++) { rowS[i2] = 0.f; posv[i2] = 0.f; }

    for (int ct = 0; ct < 32; ct++) {
        int colBase = (blockIdx.y * 32 + ct) * 128;
        __syncthreads();   // previous tile's readers done (also drains A staging)
        stage_tile(emb + (size_t)colBase * 128, shB, w, lane);
        __syncthreads();   // staging complete (compiler drains vmcnt at barrier)

        f32x4 acc[4][4];
#pragma unroll
        for (int rt = 0; rt < 4; rt++)
#pragma unroll
            for (int nt = 0; nt < 4; nt++) acc[rt][nt] = (f32x4){0.f, 0.f, 0.f, 0.f};
        mfma_tile(shA, shB, rh, ch, tx, q, acc);

        // fused epilogue: logits -> exp row-sums + positive capture
#pragma unroll
        for (int rt = 0; rt < 4; rt++) {
#pragma unroll
            for (int nt = 0; nt < 4; nt++) {
                int col = colBase + ch * 64 + nt * 16 + tx;
#pragma unroll
                for (int reg = 0; reg < 4; reg++) {
                    int row = rowBase + rh * 64 + rt * 16 + q * 4 + reg;
                    float l = acc[rt][nt][reg] * 10.0f;
                    float e = __expf(l - 10.0f);
                    rowS[rt * 4 + reg] += (col == row) ? 0.0f : e;
                    posv[rt * 4 + reg] += (col == (row ^ B_INS)) ? l : 0.0f;
                }
            }
        }
    }
    // reduce across the 16 column lanes
#pragma unroll
    for (int off = 1; off <= 8; off <<= 1) {
#pragma unroll
        for (int i2 = 0; i2 < 16; i2++) {
            rowS[i2] += __shfl_xor(rowS[i2], off, 16);
            posv[i2] += __shfl_xor(posv[i2], off, 16);
        }
    }
    if (tx == 0) {
#pragma unroll
        for (int rt = 0; rt < 4; rt++)
#pragma unroll
            for (int reg = 0; reg < 4; reg++) {
                int row = rowBase + rh * 64 + rt * 16 + q * 4 + reg;
                atomicAdd(&S[row], rowS[rt * 4 + reg]);
                atomicAdd(&pos[row], posv[rt * 4 + reg]);
            }
    }
}

// ---------------- patch CE (MFMA) ----------------
// grid (4 row-strips, 256 batches). Block: 128 rows x 512 cols of batch b's Gram.
__global__ __launch_bounds__(256) void patch_ce_mfma(const bf16_t* __restrict__ embP,
                                                     const int* __restrict__ c1,
                                                     const int* __restrict__ c2,
                                                     float* __restrict__ acc_out) {
    __shared__ __align__(16) bf16_t shA[128 * 128];
    __shared__ __align__(16) bf16_t shB[128 * 128];
    int t = threadIdx.x;
    int w = t >> 6, lane = t & 63;
    int tx = lane & 15, q = lane >> 4;
    int rh = w & 1, ch = w >> 1;
    int strip = blockIdx.x, b = blockIdx.y;
    const bf16_t* base = embP + (size_t)b * NP * D;
    int rowBase = strip * 128;

    stage_tile(base + (size_t)rowBase * 128, shA, w, lane);

    float rowS[16], posv[16];
#pragma unroll
    for (int i2 = 0; i2 < 16; i2++) { rowS[i2] = 0.f; posv[i2] = 0.f; }

    for (int ct = 0; ct < 4; ct++) {
        int colBase = ct * 128;
        __syncthreads();
        stage_tile(base + (size_t)colBase * 128, shB, w, lane);
        __syncthreads();

        f32x4 acc[4][4];
#pragma unroll
        for (int rt = 0; rt < 4; rt++)
#pragma unroll
            for (int nt = 0; nt < 4; nt++) acc[rt][nt] = (f32x4){0.f, 0.f, 0.f, 0.f};
        mfma_tile(shA, shB, rh, ch, tx, q, acc);

#pragma unroll
        for (int rt = 0; rt < 4; rt++) {
#pragma unroll
            for (int nt = 0; nt < 4; nt++) {
                int col = colBase + ch * 64 + nt * 16 + tx;
#pragma unroll
                for (int reg = 0; reg < 4; reg++) {
                    int row = rowBase + rh * 64 + rt * 16 + q * 4 + reg;
                    float l = acc[rt][nt][reg] * 10.0f;
                    float e = __expf(l - 10.0f);
                    rowS[rt * 4 + reg] += (col == row) ? 0.0f : e;
                    posv[rt * 4 + reg] += (col == (row ^ P)) ? l : 0.0f;
                }
            }
        }
    }
#pragma unroll
    for (int off = 1; off <= 8; off <<= 1) {
#pragma unroll
        for (int i2 = 0; i2 < 16; i2++) {
            rowS[i2] += __shfl_xor(rowS[i2], off, 16);
            posv[i2] += __shfl_xor(posv[i2], off, 16);
        }
    }
    // combine the two column-half waves via LDS (reuse shA as scratch)
    float* sp = (float*)shA;   // [0..256): S by (r,ch); [256..512): pos; [512..516): wave sums
    __syncthreads();           // everyone done reading shA
    if (tx == 0) {
#pragma unroll
        for (int rt = 0; rt < 4; rt++)
#pragma unroll
            for (int reg = 0; reg < 4; reg++) {
                int r = rh * 64 + rt * 16 + q * 4 + reg;
                sp[r * 2 + ch] = rowS[rt * 4 + reg];
                sp[256 + r * 2 + ch] = posv[rt * 4 + reg];
            }
    }
    __syncthreads();
    float contrib = 0.f;
    if (t < 128) {
        float Ssum = sp[t * 2] + sp[t * 2 + 1];
        float pv = sp[256 + t * 2] + sp[256 + t * 2 + 1];
        int i = rowBase + t;
        int cnt = (i < P) ? c1[b * P + i] : c2[b * P + i - P];
        contrib = (cnt != 0) ? (__logf(Ssum) + 10.0f - pv) : 0.0f;
    }
#pragma unroll
    for (int off = 32; off >= 1; off >>= 1) contrib += __shfl_down(contrib, off, 64);
    if (lane == 0) sp[512 + w] = contrib;
    __syncthreads();
    if (t == 0) atomicAdd(&acc_out[1], sp[512] + sp[513] + sp[514] + sp[515]);
}

// ---------------- finalize ----------------
__global__ void fin_ins_k(const float* __restrict__ S_ins, const float* __restrict__ pos_ins,
                          float* __restrict__ acc) {
    int i = blockIdx.x * 256 + threadIdx.x;
    float v = __logf(S_ins[i]) + 10.0f - pos_ins[i];
    int lane = threadIdx.x & 63, wave = threadIdx.x >> 6;
#pragma unroll
    for (int off = 32; off >= 1; off >>= 1) v += __shfl_down(v, off, 64);
    __shared__ float ps[4];
    if (lane == 0) ps[wave] = v;
    __syncthreads();
    if (threadIdx.x == 0) atomicAdd(&acc[0], ps[0] + ps[1] + ps[2] + ps[3]);
}

__global__ void final_k(const int* __restrict__ c1, const int* __restrict__ c2,
                        const float* __restrict__ acc, float* __restrict__ out) {
    int t = threadIdx.x;
    int cnt = 0;
    for (int i = t; i < BP * P; i += 256) {
        cnt += (c1[i] != 0) ? 1 : 0;
        cnt += (c2[i] != 0) ? 1 : 0;
    }
    float v = (float)cnt;
    int lane = t & 63, wave = t >> 6;
#pragma unroll
    for (int off = 32; off >= 1; off >>= 1) v += __shfl_down(v, off, 64);
    __shared__ float ps[4];
    if (lane == 0) ps[wave] = v;
    __syncthreads();
    if (t == 0) {
        float n_valid = ps[0] + ps[1] + ps[2] + ps[3];
        out[0] = acc[0] * (1.0f / (float)N_INS) + acc[1] / n_valid;
    }
}

// ---------------- launch ----------------
extern "C" void kernel_launch(void* const* d_in, const int* in_sizes, int n_in,
                              void* d_out, int out_size, void* d_ws, size_t ws_size,
                              hipStream_t stream) {
    const float* v1i = (const float*)d_in[0];
    const float* v2i = (const float*)d_in[1];
    const float* v1p = (const float*)d_in[2];
    const float* v2p = (const float*)d_in[3];
    const int* c1 = (const int*)d_in[4];
    const int* c2 = (const int*)d_in[5];
    float* ws = (float*)d_ws;
    float* out = (float*)d_out;
    bf16_t* embI = (bf16_t*)((char*)d_ws + EMB_I_BYTE);
    bf16_t* embP = (bf16_t*)((char*)d_ws + EMB_P_BYTE);

    hipMemsetAsync(ws, 0, WS_ZERO_FLOATS * sizeof(float), stream);

    norm_ins_k<<<N_INS / 4, 256, 0, stream>>>(v1i, v2i, embI);
    norm_patch_k<<<BP * 2 * 4, 256, 0, stream>>>(v1p, v2p, embP);

    ins_ce_mfma<<<dim3(N_INS / 128, 4), 256, 0, stream>>>(embI, ws + WS_S, ws + WS_POS);
    patch_ce_mfma<<<dim3(4, BP), 256, 0, stream>>>(embP, c1, c2, ws + WS_ACC);

    fin_ins_k<<<N_INS / 256, 256, 0, stream>>>(ws + WS_S, ws + WS_POS, ws + WS_ACC);
    final_k<<<1, 256, 0, stream>>>(c1, c2, ws + WS_ACC, out);
}

// Round 3
// 322.867 us; speedup vs baseline: 4.8918x; 1.4030x over previous
//
#include <hip/hip_runtime.h>
#include <math.h>

typedef __bf16 bf16_t;
typedef __bf16 bf16x8 __attribute__((ext_vector_type(8)));
typedef float f32x4 __attribute__((ext_vector_type(4)));

#define B_INS 8192
#define N_INS 16384
#define D 128
#define BP 256
#define P 256
#define NP 512

// exp(l-10) with l = dot*10  ==  exp2(dot*C1 - C1), C1 = 10*log2(e)
#define C1_CONST 14.426950408889634f

// ---------------- workspace layout (floats) ----------------
#define WS_ACC 0
#define WS_S 8
#define WS_POS (8 + 16384)
#define WS_SP (8 + 2 * 16384)
#define WS_PP (WS_SP + BP * NP)
#define WS_ZERO_FLOATS (WS_PP + BP * NP)
#define EMB_I_BYTE ((((WS_ZERO_FLOATS) * 4 + 15) / 16) * 16)
#define EMB_P_BYTE (EMB_I_BYTE + N_INS * D * 2)

// ---------------- staging ----------------
__device__ __forceinline__ void load_lds16(const bf16_t* g, bf16_t* l) {
    __builtin_amdgcn_global_load_lds(
        (const __attribute__((address_space(1))) void*)g,
        (__attribute__((address_space(3))) void*)l, 16, 0, 0);
}

// Stage 128x128 bf16 tile (row-major 256B rows). Wave w -> rows [w*32, +32).
__device__ __forceinline__ void stage_tile(const bf16_t* __restrict__ src,
                                           bf16_t* dst, int w, int lane) {
    const bf16_t* g = src + (size_t)(w * 32 + (lane >> 4)) * 128 + (lane & 15) * 8;
#pragma unroll
    for (int it = 0; it < 8; it++)
        load_lds16(g + (size_t)it * 4 * 128, dst + (w * 32 + it * 4) * 128);
}

// ---------------- MFMA 128x128 tile, K=128 ----------------
__device__ __forceinline__ void mfma_tile(const bf16_t* shA, const bf16_t* shB,
                                          int rh, int ch, int tx, int q,
                                          f32x4 acc[4][4]) {
#pragma unroll
    for (int ks = 0; ks < 4; ks++) {
        bf16x8 af[4], bf[4];
#pragma unroll
        for (int rt = 0; rt < 4; rt++)
            af[rt] = *(const bf16x8*)(shA + (rh * 64 + rt * 16 + tx) * 128 + ks * 32 + q * 8);
#pragma unroll
        for (int nt = 0; nt < 4; nt++)
            bf[nt] = *(const bf16x8*)(shB + (ch * 64 + nt * 16 + tx) * 128 + ks * 32 + q * 8);
#pragma unroll
        for (int rt = 0; rt < 4; rt++)
#pragma unroll
            for (int nt = 0; nt < 4; nt++)
                acc[rt][nt] = __builtin_amdgcn_mfma_f32_16x16x32_bf16(
                    af[rt], bf[nt], acc[rt][nt], 0, 0, 0);
    }
}

// ---------------- symmetric-Gram tile body ----------------
// MODE: 0 = plain (rowS + colS), 1 = diagonal (rowS only, skip in-tile diag),
//       2 = positive (rowS + colS + capture in-tile diagonal logit).
// Results: SrowL[2][128] (by ch), ScolL[2][128] (by rh), posL[128].
template <int MODE>
__device__ __forceinline__ void gram_tile_body(const bf16_t* shA, const bf16_t* shB,
                                               float* SrowL, float* ScolL,
                                               float* posL, int t) {
    int lane = t & 63, w = t >> 6;
    int tx = lane & 15, q = lane >> 4;
    int rh = w & 1, ch = w >> 1;

    f32x4 acc[4][4];
#pragma unroll
    for (int rt = 0; rt < 4; rt++)
#pragma unroll
        for (int nt = 0; nt < 4; nt++) acc[rt][nt] = (f32x4){0.f, 0.f, 0.f, 0.f};
    mfma_tile(shA, shB, rh, ch, tx, q, acc);

    float rowS[16], colS[4];
#pragma unroll
    for (int i = 0; i < 16; i++) rowS[i] = 0.f;
#pragma unroll
    for (int i = 0; i < 4; i++) colS[i] = 0.f;

#pragma unroll
    for (int rt = 0; rt < 4; rt++) {
#pragma unroll
        for (int nt = 0; nt < 4; nt++) {
#pragma unroll
            for (int reg = 0; reg < 4; reg++) {
                float e = __builtin_amdgcn_exp2f(
                    fmaf(acc[rt][nt][reg], C1_CONST, -C1_CONST));
                if (MODE == 1) {
                    int inRow = rh * 64 + rt * 16 + q * 4 + reg;
                    int inCol = ch * 64 + nt * 16 + tx;
                    e = (inRow == inCol) ? 0.f : e;
                }
                rowS[rt * 4 + reg] += e;
                if (MODE != 1) colS[nt] += e;
            }
        }
    }

    if (MODE == 2) {
        // in-tile diagonal: ch==rh, nt==rt, tx==q*4+reg
        if (ch == rh) {
            int reg = tx - q * 4;
            if (reg >= 0 && reg < 4) {
#pragma unroll
                for (int rt = 0; rt < 4; rt++)
                    posL[rh * 64 + rt * 16 + tx] = acc[rt][rt][reg] * 10.0f;
            }
        }
    }

    // rowS: reduce over the 16 tx lanes
#pragma unroll
    for (int off = 1; off <= 8; off <<= 1)
#pragma unroll
        for (int i = 0; i < 16; i++) rowS[i] += __shfl_xor(rowS[i], off, 16);
    if (tx == 0) {
#pragma unroll
        for (int rt = 0; rt < 4; rt++)
#pragma unroll
            for (int reg = 0; reg < 4; reg++)
                SrowL[ch * 128 + rh * 64 + rt * 16 + q * 4 + reg] = rowS[rt * 4 + reg];
    }
    if (MODE != 1) {
        // colS: reduce over the 4 q groups
#pragma unroll
        for (int i = 0; i < 4; i++) {
            colS[i] += __shfl_xor(colS[i], 16, 64);
            colS[i] += __shfl_xor(colS[i], 32, 64);
        }
        if (q == 0) {
#pragma unroll
            for (int nt = 0; nt < 4; nt++)
                ScolL[rh * 128 + ch * 64 + nt * 16 + tx] = colS[nt];
        }
    }
}

// ---------------- normalize kernels ----------------
__global__ __launch_bounds__(256) void norm_ins_k(const float* __restrict__ v1,
                                                  const float* __restrict__ v2,
                                                  bf16_t* __restrict__ embI) {
    int w = threadIdx.x >> 6, lane = threadIdx.x & 63;
    int i = blockIdx.x * 4 + w;
    const float* src = (i < B_INS) ? (v1 + (size_t)i * D) : (v2 + (size_t)(i - B_INS) * D);
    float2 v = *(const float2*)(src + lane * 2);
    float ss = v.x * v.x + v.y * v.y;
#pragma unroll
    for (int off = 32; off >= 1; off >>= 1) ss += __shfl_xor(ss, off, 64);
    float inv = 1.0f / fmaxf(sqrtf(ss), 1e-12f);
    union { bf16_t b[2]; unsigned u; } pk;
    pk.b[0] = (bf16_t)(v.x * inv);
    pk.b[1] = (bf16_t)(v.y * inv);
    *(unsigned*)(embI + (size_t)i * D + lane * 2) = pk.u;
}

__global__ __launch_bounds__(256) void norm_patch_k(const float* __restrict__ v1,
                                                    const float* __restrict__ v2,
                                                    bf16_t* __restrict__ embP) {
    __shared__ float L[128][65];
    __shared__ float ps[4][64];
    __shared__ float invs[64];
    int t = threadIdx.x;
    int bx = blockIdx.x;
    int b = bx >> 3, h = (bx >> 2) & 1, chunk = bx & 3;
    int i0 = chunk * 64;
    const float* src = ((h == 0) ? v1 : v2) + (size_t)b * D * P;

#pragma unroll
    for (int it = 0; it < 8; it++) {
        int fi = it * 256 + t;
        int d = fi >> 4, c4 = fi & 15;
        float4 v = *(const float4*)(src + (size_t)d * P + i0 + c4 * 4);
        L[d][c4 * 4 + 0] = v.x;
        L[d][c4 * 4 + 1] = v.y;
        L[d][c4 * 4 + 2] = v.z;
        L[d][c4 * 4 + 3] = v.w;
    }
    __syncthreads();
    {
        int col = t & 63, part = t >> 6;
        float ss = 0.f;
#pragma unroll 8
        for (int d = part * 32; d < part * 32 + 32; d++) { float x = L[d][col]; ss += x * x; }
        ps[part][col] = ss;
    }
    __syncthreads();
    if (t < 64) {
        float n2 = ps[0][t] + ps[1][t] + ps[2][t] + ps[3][t];
        invs[t] = 1.0f / fmaxf(sqrtf(n2), 1e-12f);
    }
    __syncthreads();
#pragma unroll
    for (int it = 0; it < 16; it++) {
        int idx = it * 256 + t;
        int pc = idx & 63, ic = idx >> 6;
        int d = pc * 2;
        float inv = invs[ic];
        union { bf16_t b[2]; unsigned u; } pk;
        pk.b[0] = (bf16_t)(L[d][ic] * inv);
        pk.b[1] = (bf16_t)(L[d + 1][ic] * inv);
        *(unsigned*)(embP + (size_t)b * NP * D + (size_t)(h * P + i0 + ic) * D + d) = pk.u;
    }
}

// ---------------- instance CE: one upper-triangle 128x128 tile per block ----------------
__global__ __launch_bounds__(256) void ins_tile_k(const bf16_t* __restrict__ emb,
                                                  float* __restrict__ S,
                                                  float* __restrict__ pos) {
    __shared__ __align__(16) bf16_t shA[128 * 128];
    __shared__ __align__(16) bf16_t shB[128 * 128];
    __shared__ float SrowL[256];
    __shared__ float ScolL[256];
    __shared__ float posL[128];
    int t = threadIdx.x;
    int w = t >> 6, lane = t & 63;

    // decode upper-triangular (R,C), R<=C, from linear block id
    int L = blockIdx.x;
    int R = (int)((257.0f - sqrtf(66049.0f - 8.0f * (float)L)) * 0.5f);
    if (R > 127) R = 127;
    if (R < 0) R = 0;
    while (R * (257 - R) / 2 > L) --R;
    while ((R + 1) * (257 - (R + 1)) / 2 <= L) ++R;
    int C = R + (L - R * (257 - R) / 2);
    int rowBase = R * 128, colBase = C * 128;

    stage_tile(emb + (size_t)rowBase * 128, shA, w, lane);
    if (C != R) stage_tile(emb + (size_t)colBase * 128, shB, w, lane);
    __syncthreads();   // drains global_load_lds (vmcnt before barrier)

    const bf16_t* Bp = (C == R) ? shA : shB;
    if (C == R)           gram_tile_body<1>(shA, Bp, SrowL, ScolL, posL, t);
    else if (C == R + 64) gram_tile_body<2>(shA, Bp, SrowL, ScolL, posL, t);
    else                  gram_tile_body<0>(shA, Bp, SrowL, ScolL, posL, t);

    __syncthreads();
    if (t < 128) {
        atomicAdd(&S[rowBase + t], SrowL[t] + SrowL[128 + t]);
        if (C != R) atomicAdd(&S[colBase + t], ScolL[t] + ScolL[128 + t]);
        if (C == R + 64) {
            float pl = posL[t];
            atomicAdd(&pos[rowBase + t], pl);
            atomicAdd(&pos[colBase + t], pl);
        }
    }
}

// ---------------- patch CE: 10 upper-triangle tiles per batch ----------------
__constant__ int RTAB[10] = {0, 0, 0, 0, 1, 1, 1, 2, 2, 3};
__constant__ int CTAB[10] = {0, 1, 2, 3, 1, 2, 3, 2, 3, 3};

__global__ __launch_bounds__(256) void patch_tile_k(const bf16_t* __restrict__ embP,
                                                    float* __restrict__ Sp,
                                                    float* __restrict__ posp) {
    __shared__ __align__(16) bf16_t shA[128 * 128];
    __shared__ __align__(16) bf16_t shB[128 * 128];
    __shared__ float SrowL[256];
    __shared__ float ScolL[256];
    __shared__ float posL[128];
    int t = threadIdx.x;
    int w = t >> 6, lane = t & 63;
    int ti = blockIdx.x, b = blockIdx.y;
    int R = RTAB[ti], C = CTAB[ti];
    int rowBase = R * 128, colBase = C * 128;
    const bf16_t* base = embP + (size_t)b * NP * D;
    float* Sb = Sp + (size_t)b * NP;
    float* pb = posp + (size_t)b * NP;

    stage_tile(base + (size_t)rowBase * 128, shA, w, lane);
    if (C != R) stage_tile(base + (size_t)colBase * 128, shB, w, lane);
    __syncthreads();

    const bf16_t* Bp = (C == R) ? shA : shB;
    if (C == R)          gram_tile_body<1>(shA, Bp, SrowL, ScolL, posL, t);
    else if (C == R + 2) gram_tile_body<2>(shA, Bp, SrowL, ScolL, posL, t);
    else                 gram_tile_body<0>(shA, Bp, SrowL, ScolL, posL, t);

    __syncthreads();
    if (t < 128) {
        atomicAdd(&Sb[rowBase + t], SrowL[t] + SrowL[128 + t]);
        if (C != R) atomicAdd(&Sb[colBase + t], ScolL[t] + ScolL[128 + t]);
        if (C == R + 2) {
            float pl = posL[t];
            atomicAdd(&pb[rowBase + t], pl);
            atomicAdd(&pb[colBase + t], pl);
        }
    }
}

// ---------------- finalize ----------------
__global__ void fin_ins_k(const float* __restrict__ S_ins, const float* __restrict__ pos_ins,
                          float* __restrict__ acc) {
    int i = blockIdx.x * 256 + threadIdx.x;
    float v = __logf(S_ins[i]) + 10.0f - pos_ins[i];
    int lane = threadIdx.x & 63, wave = threadIdx.x >> 6;
#pragma unroll
    for (int off = 32; off >= 1; off >>= 1) v += __shfl_down(v, off, 64);
    __shared__ float ps[4];
    if (lane == 0) ps[wave] = v;
    __syncthreads();
    if (threadIdx.x == 0) atomicAdd(&acc[0], ps[0] + ps[1] + ps[2] + ps[3]);
}

__global__ void fin_patch_k(const float* __restrict__ Sp, const float* __restrict__ posp,
                            const int* __restrict__ c1, const int* __restrict__ c2,
                            float* __restrict__ acc) {
    int idx = blockIdx.x * 256 + threadIdx.x;   // over BP*NP
    int b = idx >> 9, i = idx & 511;
    int cnt = (i < P) ? c1[b * P + i] : c2[b * P + i - P];
    float v = (cnt != 0) ? (__logf(Sp[idx]) + 10.0f - posp[idx]) : 0.f;
    int lane = threadIdx.x & 63, wave = threadIdx.x >> 6;
#pragma unroll
    for (int off = 32; off >= 1; off >>= 1) v += __shfl_down(v, off, 64);
    __shared__ float ps[4];
    if (lane == 0) ps[wave] = v;
    __syncthreads();
    if (threadIdx.x == 0) atomicAdd(&acc[1], ps[0] + ps[1] + ps[2] + ps[3]);
}

__global__ void final_k(const int* __restrict__ c1, const int* __restrict__ c2,
                        const float* __restrict__ acc, float* __restrict__ out) {
    int t = threadIdx.x;
    int cnt = 0;
    for (int i = t; i < BP * P; i += 256) {
        cnt += (c1[i] != 0) ? 1 : 0;
        cnt += (c2[i] != 0) ? 1 : 0;
    }
    float v = (float)cnt;
    int lane = t & 63, wave = t >> 6;
#pragma unroll
    for (int off = 32; off >= 1; off >>= 1) v += __shfl_down(v, off, 64);
    __shared__ float ps[4];
    if (lane == 0) ps[wave] = v;
    __syncthreads();
    if (t == 0) {
        float n_valid = ps[0] + ps[1] + ps[2] + ps[3];
        out[0] = acc[0] * (1.0f / (float)N_INS) + acc[1] / n_valid;
    }
}

// ---------------- launch ----------------
extern "C" void kernel_launch(void* const* d_in, const int* in_sizes, int n_in,
                              void* d_out, int out_size, void* d_ws, size_t ws_size,
                              hipStream_t stream) {
    const float* v1i = (const float*)d_in[0];
    const float* v2i = (const float*)d_in[1];
    const float* v1p = (const float*)d_in[2];
    const float* v2p = (const float*)d_in[3];
    const int* c1 = (const int*)d_in[4];
    const int* c2 = (const int*)d_in[5];
    float* ws = (float*)d_ws;
    float* out = (float*)d_out;
    bf16_t* embI = (bf16_t*)((char*)d_ws + EMB_I_BYTE);
    bf16_t* embP = (bf16_t*)((char*)d_ws + EMB_P_BYTE);

    hipMemsetAsync(ws, 0, WS_ZERO_FLOATS * sizeof(float), stream);

    norm_ins_k<<<N_INS / 4, 256, 0, stream>>>(v1i, v2i, embI);
    norm_patch_k<<<BP * 2 * 4, 256, 0, stream>>>(v1p, v2p, embP);

    ins_tile_k<<<8256, 256, 0, stream>>>(embI, ws + WS_S, ws + WS_POS);
    patch_tile_k<<<dim3(10, BP), 256, 0, stream>>>(embP, ws + WS_SP, ws + WS_PP);

    fin_ins_k<<<N_INS / 256, 256, 0, stream>>>(ws + WS_S, ws + WS_POS, ws + WS_ACC);
    fin_patch_k<<<(BP * NP) / 256, 256, 0, stream>>>(ws + WS_SP, ws + WS_PP, c1, c2, ws + WS_ACC);
    final_k<<<1, 256, 0, stream>>>(c1, c2, ws + WS_ACC, out);
}

// Round 4
// 289.532 us; speedup vs baseline: 5.4551x; 1.1151x over previous
//
#include <hip/hip_runtime.h>
#include <math.h>

typedef __bf16 bf16_t;
typedef __bf16 bf16x8 __attribute__((ext_vector_type(8)));
typedef float f32x4 __attribute__((ext_vector_type(4)));

#define B_INS 8192
#define N_INS 16384
#define D 128
#define BP 256
#define P 256
#define NP 512

// exp(l-10) with l = dot*10  ==  exp2(dot*C1 - C1), C1 = 10*log2(e)
#define C1_CONST 14.426950408889634f

// ---------------- workspace layout (floats) ----------------
#define WS_ACC 0
#define WS_S 8
#define WS_POS (8 + 16384)
#define WS_SP (8 + 2 * 16384)
#define WS_PP (WS_SP + BP * NP)
#define WS_ZERO_FLOATS (WS_PP + BP * NP)
#define EMB_I_BYTE ((((WS_ZERO_FLOATS) * 4 + 15) / 16) * 16)
#define EMB_P_BYTE (EMB_I_BYTE + N_INS * D * 2)

// Panel layout: global row i, k -> panel p=i>>7, r=i&127, g=k>>3, j=k&7
// elem offset = (p<<14) + (g<<10) + (r<<3) + j. One panel = 16384 elems = 32 KB,
// contiguous, so staging is a linear copy; fragment ds_read_b128 addresses are
// gi*2048 + R*16 bytes -> banks (R*4+c)%32: even 4-per-bank across a 32-lane
// phase (structural minimum for b128, no excess conflicts).

// ---------------- staging: linear 32 KB panel copy ----------------
__device__ __forceinline__ void load_lds16(const bf16_t* g, bf16_t* l) {
    __builtin_amdgcn_global_load_lds(
        (const __attribute__((address_space(1))) void*)g,
        (__attribute__((address_space(3))) void*)l, 16, 0, 0);
}

__device__ __forceinline__ void stage_panel(const bf16_t* __restrict__ src,
                                            bf16_t* dst, int w, int lane) {
    const bf16_t* g = src + w * 4096 + lane * 8;
    bf16_t* d = dst + w * 4096;
#pragma unroll
    for (int it = 0; it < 8; it++)
        load_lds16(g + it * 512, d + it * 512);
}

// ---------------- MFMA 128x128 tile, K=128, group-major LDS ----------------
__device__ __forceinline__ void mfma_tile(const bf16_t* shA, const bf16_t* shB,
                                          int rh, int ch, int tx, int q,
                                          f32x4 acc[4][4]) {
#pragma unroll
    for (int ks = 0; ks < 4; ks++) {
        int gi = ks * 4 + q;
        bf16x8 af[4], bf[4];
#pragma unroll
        for (int rt = 0; rt < 4; rt++)
            af[rt] = *(const bf16x8*)(shA + (gi << 10) + ((rh * 64 + rt * 16 + tx) << 3));
#pragma unroll
        for (int nt = 0; nt < 4; nt++)
            bf[nt] = *(const bf16x8*)(shB + (gi << 10) + ((ch * 64 + nt * 16 + tx) << 3));
#pragma unroll
        for (int rt = 0; rt < 4; rt++)
#pragma unroll
            for (int nt = 0; nt < 4; nt++)
                acc[rt][nt] = __builtin_amdgcn_mfma_f32_16x16x32_bf16(
                    af[rt], bf[nt], acc[rt][nt], 0, 0, 0);
    }
}

// ---------------- tile epilogue (shared by ins/patch) ----------------
// Computes exp sums; accumulates rowS in registers; flushes colS/pos atomics.
__device__ __forceinline__ void tile_epilogue(const f32x4 acc[4][4], bool isDiag,
                                              bool isPos, int rowBase, int colBase,
                                              int rh, int ch, int tx, int q,
                                              float rowS[16],
                                              float* __restrict__ S,
                                              float* __restrict__ pos) {
    float colS[4] = {0.f, 0.f, 0.f, 0.f};
#pragma unroll
    for (int rt = 0; rt < 4; rt++) {
#pragma unroll
        for (int nt = 0; nt < 4; nt++) {
#pragma unroll
            for (int reg = 0; reg < 4; reg++) {
                float e = __builtin_amdgcn_exp2f(
                    fmaf(acc[rt][nt][reg], C1_CONST, -C1_CONST));
                if (isDiag) {
                    int inRow = rh * 64 + rt * 16 + q * 4 + reg;
                    int inCol = ch * 64 + nt * 16 + tx;
                    e = (inRow == inCol) ? 0.f : e;
                }
                rowS[rt * 4 + reg] += e;
                colS[nt] += e;
            }
        }
    }
    if (!isDiag) {
#pragma unroll
        for (int i = 0; i < 4; i++) {
            colS[i] += __shfl_xor(colS[i], 16, 64);
            colS[i] += __shfl_xor(colS[i], 32, 64);
        }
        if (q == 0) {
#pragma unroll
            for (int nt = 0; nt < 4; nt++)
                atomicAdd(&S[colBase + ch * 64 + nt * 16 + tx], colS[nt]);
        }
    }
    if (isPos && ch == rh) {
        int reg = tx - q * 4;
        if (reg >= 0 && reg < 4) {
#pragma unroll
            for (int rt = 0; rt < 4; rt++) {
                float pl = acc[rt][rt][reg] * 10.0f;
                atomicAdd(&pos[rowBase + rh * 64 + rt * 16 + tx], pl);
                atomicAdd(&pos[colBase + rh * 64 + rt * 16 + tx], pl);
            }
        }
    }
}

__device__ __forceinline__ void flush_rowS(float rowS[16], int rowBase,
                                           int rh, int tx, int q,
                                           float* __restrict__ S) {
#pragma unroll
    for (int off = 1; off <= 8; off <<= 1)
#pragma unroll
        for (int i = 0; i < 16; i++) rowS[i] += __shfl_xor(rowS[i], off, 16);
    if (tx == 0) {
#pragma unroll
        for (int rt = 0; rt < 4; rt++)
#pragma unroll
            for (int reg = 0; reg < 4; reg++)
                atomicAdd(&S[rowBase + rh * 64 + rt * 16 + q * 4 + reg],
                          rowS[rt * 4 + reg]);
    }
}

// ---------------- normalize kernels (write panel layout) ----------------
__global__ __launch_bounds__(256) void norm_ins_k(const float* __restrict__ v1,
                                                  const float* __restrict__ v2,
                                                  bf16_t* __restrict__ embI) {
    int w = threadIdx.x >> 6, lane = threadIdx.x & 63;
    int i = blockIdx.x * 4 + w;
    const float* src = (i < B_INS) ? (v1 + (size_t)i * D) : (v2 + (size_t)(i - B_INS) * D);
    float2 v = *(const float2*)(src + lane * 2);
    float ss = v.x * v.x + v.y * v.y;
#pragma unroll
    for (int off = 32; off >= 1; off >>= 1) ss += __shfl_xor(ss, off, 64);
    float inv = 1.0f / fmaxf(sqrtf(ss), 1e-12f);
    union { bf16_t b[2]; unsigned u; } pk;
    pk.b[0] = (bf16_t)(v.x * inv);
    pk.b[1] = (bf16_t)(v.y * inv);
    // k = 2*lane: g = lane>>2, j = 2*(lane&3)
    size_t off = ((size_t)(i >> 7) << 14) + ((size_t)(lane >> 2) << 10) +
                 ((size_t)(i & 127) << 3) + ((lane & 3) << 1);
    *(unsigned*)(embI + off) = pk.u;
}

__global__ __launch_bounds__(256) void norm_patch_k(const float* __restrict__ v1,
                                                    const float* __restrict__ v2,
                                                    bf16_t* __restrict__ embP) {
    __shared__ float L[128][65];
    __shared__ float ps[4][64];
    __shared__ float invs[64];
    int t = threadIdx.x;
    int bx = blockIdx.x;
    int b = bx >> 3, h = (bx >> 2) & 1, chunk = bx & 3;
    int i0 = chunk * 64;
    const float* src = ((h == 0) ? v1 : v2) + (size_t)b * D * P;

#pragma unroll
    for (int it = 0; it < 8; it++) {
        int fi = it * 256 + t;
        int d = fi >> 4, c4 = fi & 15;
        float4 v = *(const float4*)(src + (size_t)d * P + i0 + c4 * 4);
        L[d][c4 * 4 + 0] = v.x;
        L[d][c4 * 4 + 1] = v.y;
        L[d][c4 * 4 + 2] = v.z;
        L[d][c4 * 4 + 3] = v.w;
    }
    __syncthreads();
    {
        int col = t & 63, part = t >> 6;
        float ss = 0.f;
#pragma unroll 8
        for (int d = part * 32; d < part * 32 + 32; d++) { float x = L[d][col]; ss += x * x; }
        ps[part][col] = ss;
    }
    __syncthreads();
    if (t < 64) {
        float n2 = ps[0][t] + ps[1][t] + ps[2][t] + ps[3][t];
        invs[t] = 1.0f / fmaxf(sqrtf(n2), 1e-12f);
    }
    __syncthreads();
#pragma unroll
    for (int it = 0; it < 16; it++) {
        int idx = it * 256 + t;
        int pc = idx & 63, ic = idx >> 6;
        int d = pc * 2;
        float inv = invs[ic];
        union { bf16_t b[2]; unsigned u; } pk;
        pk.b[0] = (bf16_t)(L[d][ic] * inv);
        pk.b[1] = (bf16_t)(L[d + 1][ic] * inv);
        int iLoc = h * P + i0 + ic;   // row within batch, [0,512)
        size_t off = ((size_t)b << 16) + ((size_t)(iLoc >> 7) << 14) +
                     ((size_t)(pc >> 2) << 10) + ((size_t)(iLoc & 127) << 3) +
                     ((pc & 3) << 1);
        *(unsigned*)(embP + off) = pk.u;
    }
}

// ---------------- instance CE: panel-chunk blocks ----------------
// Block = (row panel R, chunk of up to 8 C-tiles). Stage A once, loop B tiles.
__global__ __launch_bounds__(256) void ins_panel_k(const bf16_t* __restrict__ emb,
                                                   float* __restrict__ S,
                                                   float* __restrict__ pos) {
    __shared__ __align__(16) bf16_t shA[16384];
    __shared__ __align__(16) bf16_t shB[16384];
    int t = threadIdx.x, w = t >> 6, lane = t & 63;
    int tx = lane & 15, q = lane >> 4;
    int rh = w & 1, ch = w >> 1;

    // decode: octet k has 8 panels x (16-k) chunks
    int bid = blockIdx.x, k = 0, cum = 0;
    while (bid >= cum + 8 * (16 - k)) { cum += 8 * (16 - k); k++; }
    int rem = bid - cum;
    int cc = 16 - k;
    int R = 8 * k + rem / cc;
    int ci = rem - (rem / cc) * cc;
    int c0 = R + ci * 8;
    int ntiles = min(8, 128 - c0);
    int rowBase = R * 128;

    stage_panel(emb + ((size_t)R << 14), shA, w, lane);

    float rowS[16];
#pragma unroll
    for (int i = 0; i < 16; i++) rowS[i] = 0.f;

    for (int ti = 0; ti < ntiles; ti++) {
        int C = c0 + ti;
        __syncthreads();
        if (C != R) stage_panel(emb + ((size_t)C << 14), shB, w, lane);
        __syncthreads();   // vmcnt drained before barrier -> staging visible
        const bf16_t* Bp = (C == R) ? shA : shB;

        f32x4 acc[4][4];
#pragma unroll
        for (int rt = 0; rt < 4; rt++)
#pragma unroll
            for (int nt = 0; nt < 4; nt++) acc[rt][nt] = (f32x4){0.f, 0.f, 0.f, 0.f};
        mfma_tile(shA, Bp, rh, ch, tx, q, acc);

        tile_epilogue(acc, C == R, C == R + 64, rowBase, C * 128,
                      rh, ch, tx, q, rowS, S, pos);
    }
    flush_rowS(rowS, rowBase, rh, tx, q, S);
}

// ---------------- patch CE: 10 upper-triangle tiles per batch ----------------
__constant__ int RTAB[10] = {0, 0, 0, 0, 1, 1, 1, 2, 2, 3};
__constant__ int CTAB[10] = {0, 1, 2, 3, 1, 2, 3, 2, 3, 3};

__global__ __launch_bounds__(256) void patch_tile_k(const bf16_t* __restrict__ embP,
                                                    float* __restrict__ Sp,
                                                    float* __restrict__ posp) {
    __shared__ __align__(16) bf16_t shA[16384];
    __shared__ __align__(16) bf16_t shB[16384];
    int t = threadIdx.x, w = t >> 6, lane = t & 63;
    int tx = lane & 15, q = lane >> 4;
    int rh = w & 1, ch = w >> 1;
    int ti = blockIdx.x, b = blockIdx.y;
    int R = RTAB[ti], C = CTAB[ti];
    const bf16_t* base = embP + ((size_t)b << 16);
    float* Sb = Sp + (size_t)b * NP;
    float* pb = posp + (size_t)b * NP;

    stage_panel(base + ((size_t)R << 14), shA, w, lane);
    if (C != R) stage_panel(base + ((size_t)C << 14), shB, w, lane);
    __syncthreads();
    const bf16_t* Bp = (C == R) ? shA : shB;

    f32x4 acc[4][4];
#pragma unroll
    for (int rt = 0; rt < 4; rt++)
#pragma unroll
        for (int nt = 0; nt < 4; nt++) acc[rt][nt] = (f32x4){0.f, 0.f, 0.f, 0.f};
    mfma_tile(shA, Bp, rh, ch, tx, q, acc);

    float rowS[16];
#pragma unroll
    for (int i = 0; i < 16; i++) rowS[i] = 0.f;
    tile_epilogue(acc, C == R, C == R + 2, R * 128, C * 128,
                  rh, ch, tx, q, rowS, Sb, pb);
    flush_rowS(rowS, R * 128, rh, tx, q, Sb);
}

// ---------------- finalize ----------------
__global__ void fin_ins_k(const float* __restrict__ S_ins, const float* __restrict__ pos_ins,
                          float* __restrict__ acc) {
    int i = blockIdx.x * 256 + threadIdx.x;
    float v = __logf(S_ins[i]) + 10.0f - pos_ins[i];
    int lane = threadIdx.x & 63, wave = threadIdx.x >> 6;
#pragma unroll
    for (int off = 32; off >= 1; off >>= 1) v += __shfl_down(v, off, 64);
    __shared__ float ps[4];
    if (lane == 0) ps[wave] = v;
    __syncthreads();
    if (threadIdx.x == 0) atomicAdd(&acc[0], ps[0] + ps[1] + ps[2] + ps[3]);
}

__global__ void fin_patch_k(const float* __restrict__ Sp, const float* __restrict__ posp,
                            const int* __restrict__ c1, const int* __restrict__ c2,
                            float* __restrict__ acc) {
    int idx = blockIdx.x * 256 + threadIdx.x;   // over BP*NP
    int b = idx >> 9, i = idx & 511;
    int cnt = (i < P) ? c1[b * P + i] : c2[b * P + i - P];
    float v = (cnt != 0) ? (__logf(Sp[idx]) + 10.0f - posp[idx]) : 0.f;
    int lane = threadIdx.x & 63, wave = threadIdx.x >> 6;
#pragma unroll
    for (int off = 32; off >= 1; off >>= 1) v += __shfl_down(v, off, 64);
    __shared__ float ps[4];
    if (lane == 0) ps[wave] = v;
    __syncthreads();
    if (threadIdx.x == 0) atomicAdd(&acc[1], ps[0] + ps[1] + ps[2] + ps[3]);
}

__global__ void final_k(const int* __restrict__ c1, const int* __restrict__ c2,
                        const float* __restrict__ acc, float* __restrict__ out) {
    int t = threadIdx.x;
    int cnt = 0;
    for (int i = t; i < BP * P; i += 256) {
        cnt += (c1[i] != 0) ? 1 : 0;
        cnt += (c2[i] != 0) ? 1 : 0;
    }
    float v = (float)cnt;
    int lane = t & 63, wave = t >> 6;
#pragma unroll
    for (int off = 32; off >= 1; off >>= 1) v += __shfl_down(v, off, 64);
    __shared__ float ps[4];
    if (lane == 0) ps[wave] = v;
    __syncthreads();
    if (t == 0) {
        float n_valid = ps[0] + ps[1] + ps[2] + ps[3];
        out[0] = acc[0] * (1.0f / (float)N_INS) + acc[1] / n_valid;
    }
}

// ---------------- launch ----------------
extern "C" void kernel_launch(void* const* d_in, const int* in_sizes, int n_in,
                              void* d_out, int out_size, void* d_ws, size_t ws_size,
                              hipStream_t stream) {
    const float* v1i = (const float*)d_in[0];
    const float* v2i = (const float*)d_in[1];
    const float* v1p = (const float*)d_in[2];
    const float* v2p = (const float*)d_in[3];
    const int* c1 = (const int*)d_in[4];
    const int* c2 = (const int*)d_in[5];
    float* ws = (float*)d_ws;
    float* out = (float*)d_out;
    bf16_t* embI = (bf16_t*)((char*)d_ws + EMB_I_BYTE);
    bf16_t* embP = (bf16_t*)((char*)d_ws + EMB_P_BYTE);

    hipMemsetAsync(ws, 0, WS_ZERO_FLOATS * sizeof(float), stream);

    norm_ins_k<<<N_INS / 4, 256, 0, stream>>>(v1i, v2i, embI);
    norm_patch_k<<<BP * 2 * 4, 256, 0, stream>>>(v1p, v2p, embP);

    ins_panel_k<<<1088, 256, 0, stream>>>(embI, ws + WS_S, ws + WS_POS);
    patch_tile_k<<<dim3(10, BP), 256, 0, stream>>>(embP, ws + WS_SP, ws + WS_PP);

    fin_ins_k<<<N_INS / 256, 256, 0, stream>>>(ws + WS_S, ws + WS_POS, ws + WS_ACC);
    fin_patch_k<<<(BP * NP) / 256, 256, 0, stream>>>(ws + WS_SP, ws + WS_PP, c1, c2, ws + WS_ACC);
    final_k<<<1, 256, 0, stream>>>(c1, c2, ws + WS_ACC, out);
}